// Round 1
// baseline (259.166 us; speedup 1.0000x reference)
//
#include <hip/hip_runtime.h>
#include <hip/hip_bf16.h>

#define B_ 4
#define T_ 2048
#define E_ 1024
#define H_ 16
#define DH_ 64
#define QSCALE_ 0.18033688f   // 0.125 * log2(e): QK^T comes out in log2 domain

typedef __attribute__((ext_vector_type(8))) short bf16x8;
typedef __attribute__((ext_vector_type(4))) float f32x4;
typedef unsigned int u32;

__device__ inline ushort f2bf(float f) {
    union { float f; unsigned u; } v; v.f = f;
    unsigned r = (v.u + 0x7fffu + ((v.u >> 16) & 1u)) >> 16;
    return (ushort)r;
}

// pack two f32 -> two bf16 (truncation) in one v_perm_b32: a->low, b->high
__device__ inline u32 pack2bf(float a, float b) {
    union { float f; u32 u; } ua, ub; ua.f = a; ub.f = b;
    return __builtin_amdgcn_perm(ub.u, ua.u, 0x07060302);
}

__device__ inline void gload16(const ushort* g, ushort* l) {
    __builtin_amdgcn_global_load_lds((const __attribute__((address_space(1))) u32*)g,
                                     (__attribute__((address_space(3))) u32*)l, 16, 0, 0);
}

// ---------------- fused f32 -> bf16 convert ----------------
__global__ void cvt_all(const float* __restrict__ x, const float* __restrict__ wq,
                        const float* __restrict__ wp,
                        ushort* __restrict__ xo, ushort* __restrict__ wqo, ushort* __restrict__ wpo)
{
    const int NX = B_ * T_ * E_ / 4;
    const int NW = 3 * E_ * E_ / 4;
    int i = blockIdx.x * 256 + threadIdx.x;
    const float* s; ushort* d; int off;
    if (i < NX)            { s = x;  d = xo;  off = i; }
    else if (i < NX + NW)  { s = wq; d = wqo; off = i - NX; }
    else                   { s = wp; d = wpo; off = i - NX - NW; }
    float4 f = ((const float4*)s)[off];
    ushort4 u;
    u.x = f2bf(f.x); u.y = f2bf(f.y); u.z = f2bf(f.z); u.w = f2bf(f.w);
    ((ushort4*)d)[off] = u;
}

// ===========================================================================
// Pipelined GEMM core: 256x128 tile, BK=32, 512 threads (8 waves as 4M x 2N),
// depth-4 LDS ring (96 KiB), counted vmcnt(6), raw s_barrier, setprio MFMA.
// LDS swizzle: 16B unit u of row r stored at unit position u ^ (r&3)
// (pre-swizzled global source, linear global_load_lds dst; reads conflict-free).
// ===========================================================================

// stage tile t_ (A: 256x32 via 2 loads, B: 128x32 via 1 load) into segment t_&3
#define STAGE3(t_) { const int ss_ = (t_) & 3; const int sk_ = (t_) * 32;      \
    gload16(gA0 + sk_, &As[ss_][wave * 512]);                                  \
    gload16(gA1 + sk_, &As[ss_][4096 + wave * 512]);                           \
    gload16(gB0 + sk_, &Bs[ss_][wave * 512]); }

// one phase = one K-tile: ds-read frags | stage t+3 | vmcnt(N) | barrier |
// lgkmcnt(0)+sched_barrier | setprio(1) 16xMFMA setprio(0) | barrier
#define GPHASE(t_, vmstr_, DOSTAGE_, ...) do {                                 \
    const int seg_ = (t_) & 3;                                                 \
    bf16x8 afr[4], bfr[4];                                                     \
    _Pragma("unroll") for (int i_ = 0; i_ < 4; i_++)                           \
        afr[i_] = *(const bf16x8*)&As[seg_][(mbase + i_ * 16 + lrow) * 32 + usw]; \
    _Pragma("unroll") for (int j_ = 0; j_ < 4; j_++)                           \
        bfr[j_] = *(const bf16x8*)&Bs[seg_][(nbase + j_ * 16 + lrow) * 32 + usw]; \
    if (DOSTAGE_) STAGE3((t_) + 3);                                            \
    asm volatile("s_waitcnt " vmstr_ ::: "memory");                            \
    __builtin_amdgcn_s_barrier();                                              \
    asm volatile("s_waitcnt lgkmcnt(0)" ::: "memory");                         \
    __builtin_amdgcn_sched_barrier(0);                                         \
    __builtin_amdgcn_s_setprio(1);                                             \
    __VA_ARGS__                                                                \
    __builtin_amdgcn_s_setprio(0);                                             \
    __builtin_amdgcn_sched_barrier(0);                                         \
    __builtin_amdgcn_s_barrier();                                              \
    __builtin_amdgcn_sched_barrier(0);                                         \
} while (0)

#define MFMA_QKV                                                               \
    if (ct) {                                                                  \
        _Pragma("unroll") for (int i_ = 0; i_ < 4; i_++)                       \
        _Pragma("unroll") for (int j_ = 0; j_ < 4; j_++)                       \
            acc[i_][j_] = __builtin_amdgcn_mfma_f32_16x16x32_bf16(bfr[j_], afr[i_], acc[i_][j_], 0, 0, 0); \
    } else {                                                                   \
        _Pragma("unroll") for (int i_ = 0; i_ < 4; i_++)                       \
        _Pragma("unroll") for (int j_ = 0; j_ < 4; j_++)                       \
            acc[i_][j_] = __builtin_amdgcn_mfma_f32_16x16x32_bf16(afr[i_], bfr[j_], acc[i_][j_], 0, 0, 0); \
    }

#define MFMA_CT                                                                \
    _Pragma("unroll") for (int i_ = 0; i_ < 4; i_++)                           \
    _Pragma("unroll") for (int j_ = 0; j_ < 4; j_++)                           \
        acc[i_][j_] = __builtin_amdgcn_mfma_f32_16x16x32_bf16(bfr[j_], afr[i_], acc[i_][j_], 0, 0, 0);

// ---------------- QKV GEMM ----------------
__global__ __launch_bounds__(512, 2) void gemm_qkv(
    const ushort* __restrict__ Xb, const ushort* __restrict__ Wb,
    const float* __restrict__ bias,
    ushort* __restrict__ Q, ushort* __restrict__ K, ushort* __restrict__ Vt)
{
    __shared__ ushort As[4][256 * 32];   // 64 KiB
    __shared__ ushort Bs[4][128 * 32];   // 32 KiB
    const int m0 = blockIdx.x * 256;
    const int n0 = blockIdx.y * 128;
    const int kind = n0 >> 10;           // 0=Q 1=K 2=V (block-uniform; 128 | 1024)
    const int tid  = threadIdx.x;
    const int wave = tid >> 6, lane = tid & 63;
    const int lrow = lane & 15, quad = lane >> 4;
    const int mbase = (wave >> 1) * 64;  // 4 M-slices of 64
    const int nbase = (wave & 1) * 64;   // 2 N-slices of 64
    const int usw = (quad ^ (lrow & 3)) * 8;     // swizzled unit offset (shorts)
    const int sR = lane >> 2;                    // staging row within 16-row group
    const int su = ((lane & 3) ^ (sR & 3)) * 8;  // pre-swizzled source col (shorts)

    const ushort* gA0 = Xb + (size_t)(m0 + wave * 16 + sR) * 1024 + su;
    const ushort* gA1 = gA0 + (size_t)128 * 1024;
    const ushort* gB0 = Wb + (size_t)(n0 + wave * 16 + sR) * 1024 + su;

    const int b = m0 >> 11;              // batch (256 | 2048)
    const bool ct = (kind != 2);

    f32x4 acc[4][4];
#pragma unroll
    for (int i = 0; i < 4; i++)
#pragma unroll
        for (int j = 0; j < 4; j++) acc[i][j] = f32x4{0.f, 0.f, 0.f, 0.f};

    // prologue: stage tiles 0,1,2; wait tile 0 (6 loads of tiles 1,2 in flight)
    STAGE3(0); STAGE3(1); STAGE3(2);
    asm volatile("s_waitcnt vmcnt(6)" ::: "memory");
    __builtin_amdgcn_s_barrier();
    __builtin_amdgcn_sched_barrier(0);

#pragma unroll 4
    for (int t = 0; t < 29; t++) GPHASE(t, "vmcnt(6)", 1, MFMA_QKV);
    GPHASE(29, "vmcnt(3)", 0, MFMA_QKV);
    GPHASE(30, "vmcnt(0)", 0, MFMA_QKV);
    GPHASE(31, "vmcnt(0)", 0, MFMA_QKV);

    if (ct) {
        // C^T: lane holds m = mbase+i*16+lrow, n = nbase+j*16+quad*4+r -> ushort4 along d
        ushort* dst = (kind == 0) ? Q : K;
        const float scale = (kind == 0) ? QSCALE_ : 1.f;
#pragma unroll
        for (int j = 0; j < 4; j++) {
            int nq = (n0 & 1023) + nbase + j * 16 + quad * 4;
            int h = nq >> 6, d = nq & 63;
            float4 bv = *(const float4*)&bias[n0 + nbase + j * 16 + quad * 4];
            size_t bh = (size_t)(b * H_ + h);
#pragma unroll
            for (int i = 0; i < 4; i++) {
                int t = (m0 + mbase + i * 16 + lrow) & 2047;   // batch-local!
                ushort4 o;
                o.x = f2bf((acc[i][j][0] + bv.x) * scale);
                o.y = f2bf((acc[i][j][1] + bv.y) * scale);
                o.z = f2bf((acc[i][j][2] + bv.z) * scale);
                o.w = f2bf((acc[i][j][3] + bv.w) * scale);
                *(ushort4*)&dst[(bh * T_ + t) * DH_ + d] = o;
            }
        }
    } else {
        // normal: lane holds n = nbase+j*16+lrow, t = mbase+i*16+quad*4+r -> ushort4 along t
#pragma unroll
        for (int j = 0; j < 4; j++) {
            int nv = (n0 & 1023) + nbase + j * 16 + lrow;
            int h = nv >> 6, d = nv & 63;
            float bv = bias[n0 + nbase + j * 16 + lrow];
            size_t bh = (size_t)(b * H_ + h);
#pragma unroll
            for (int i = 0; i < 4; i++) {
                int t = (m0 + mbase + i * 16 + quad * 4) & 2047;   // batch-local!
                ushort4 o;
                o.x = f2bf(acc[i][j][0] + bv);
                o.y = f2bf(acc[i][j][1] + bv);
                o.z = f2bf(acc[i][j][2] + bv);
                o.w = f2bf(acc[i][j][3] + bv);
                *(ushort4*)&Vt[(bh * DH_ + d) * T_ + t] = o;
            }
        }
    }
}

// ---------------- Flash attention: paired q-tiles (R8-proven version) ----------------
#define LDT_ 76

__global__ __launch_bounds__(256) void flash_attn(
    const ushort* __restrict__ Q, const ushort* __restrict__ K,
    const ushort* __restrict__ Vg,   // [bh][DH][T]
    ushort* __restrict__ O)
{
    __shared__ ushort Ks[64 * LDT_];
    __shared__ ushort Vt[64 * LDT_];
    __shared__ ushort Ps[128 * LDT_];   // doubles as Q staging

    const int qtA = 15 - blockIdx.x;     // long tile
    const int qtB = blockIdx.x;          // short tile
    const int bh = blockIdx.y;
    const int tid  = threadIdx.x;
    const int wave = tid >> 6, lane = tid & 63;
    const int lrow = lane & 15, quad = lane >> 4;
    const int sr = tid >> 2, sc = (tid & 3) * 16;   // K/V staging coords

    const ushort* Qbh = Q  + (size_t)bh * T_ * DH_;
    const ushort* Kbh = K  + (size_t)bh * T_ * DH_;
    const ushort* Vbh = Vg + (size_t)bh * DH_ * T_;
    const int b_ = bh >> 4, h_ = bh & 15;

    auto stageQ = [&](int qt, bf16x8 qa[2][2]) {
        int qr = tid >> 1, qc = (tid & 1) * 32;
        const ushort* src = &Qbh[(size_t)(qt * 128 + qr) * DH_ + qc];
#pragma unroll
        for (int i = 0; i < 4; i++)
            *(int4*)&Ps[qr * LDT_ + qc + 8 * i] = *(const int4*)&src[8 * i];
        __syncthreads();
#pragma unroll
        for (int s = 0; s < 2; s++)
#pragma unroll
            for (int h = 0; h < 2; h++)
                qa[s][h] = *(const bf16x8*)&Ps[(s * 64 + wave * 16 + lrow) * LDT_ + h * 32 + quad * 8];
    };

    bf16x8 qaA[2][2], qaB[2][2];
    stageQ(qtA, qaA);
    __syncthreads();
    stageQ(qtB, qaB);

    auto run = [&](const bf16x8 (&qa)[2][2], int qt) {
        const int lastkt = 2 * qt + 1;

        int4 kr0 = *(const int4*)&Kbh[(size_t)sr * DH_ + sc];
        int4 kr1 = *(const int4*)&Kbh[(size_t)sr * DH_ + sc + 8];
        int4 vr0 = *(const int4*)&Vbh[(size_t)sr * T_ + sc];
        int4 vr1 = *(const int4*)&Vbh[(size_t)sr * T_ + sc + 8];

        float ls[2] = {0.f, 0.f};
        f32x4 accO[2][4];
#pragma unroll
        for (int s = 0; s < 2; s++)
#pragma unroll
            for (int j = 0; j < 4; j++) accO[s][j] = f32x4{0.f, 0.f, 0.f, 0.f};

        for (int kt = 0; kt <= lastkt; ++kt) {
            __syncthreads();
            *(int4*)&Ks[sr * LDT_ + sc]     = kr0;
            *(int4*)&Ks[sr * LDT_ + sc + 8] = kr1;
            *(int4*)&Vt[sr * LDT_ + sc]     = vr0;
            *(int4*)&Vt[sr * LDT_ + sc + 8] = vr1;
            __syncthreads();
            if (kt < lastkt) {
                kr0 = *(const int4*)&Kbh[(size_t)((kt + 1) * 64 + sr) * DH_ + sc];
                kr1 = *(const int4*)&Kbh[(size_t)((kt + 1) * 64 + sr) * DH_ + sc + 8];
                vr0 = *(const int4*)&Vbh[(size_t)sr * T_ + (kt + 1) * 64 + sc];
                vr1 = *(const int4*)&Vbh[(size_t)sr * T_ + (kt + 1) * 64 + sc + 8];
            }

            bf16x8 kb0[4], kb1[4];
#pragma unroll
            for (int j = 0; j < 4; j++) {
                kb0[j] = *(const bf16x8*)&Ks[(j * 16 + lrow) * LDT_ + quad * 8];
                kb1[j] = *(const bf16x8*)&Ks[(j * 16 + lrow) * LDT_ + 32 + quad * 8];
            }

            const bool do0 = (kt != lastkt);
#pragma unroll
            for (int s = 0; s < 2; s++) {
                if (s == 0 && !do0) continue;
                f32x4 st[4];
#pragma unroll
                for (int j = 0; j < 4; j++) {
                    f32x4 sj = f32x4{0.f, 0.f, 0.f, 0.f};
                    sj = __builtin_amdgcn_mfma_f32_16x16x32_bf16(kb0[j], qa[s][0], sj, 0, 0, 0);
                    sj = __builtin_amdgcn_mfma_f32_16x16x32_bf16(kb1[j], qa[s][1], sj, 0, 0, 0);
                    st[j] = sj;
                }
                if (kt == 2 * qt + s) {
                    const int qrow = qt * 128 + s * 64 + wave * 16 + lrow;
                    const int keyb = kt * 64 + quad * 4;
#pragma unroll
                    for (int j = 0; j < 4; j++)
#pragma unroll
                        for (int r = 0; r < 4; r++)
                            if (keyb + j * 16 + r > qrow) st[j][r] = -1e30f;
                }
                float lp = 0.f;
#pragma unroll
                for (int j = 0; j < 4; j++)
#pragma unroll
                    for (int r = 0; r < 4; r++) {
                        float p = __builtin_amdgcn_exp2f(st[j][r]);
                        st[j][r] = p;
                        lp += p;
                    }
                ls[s] += lp;
                ushort* prow = &Ps[(s * 64 + wave * 16 + lrow) * LDT_ + quad * 4];
#pragma unroll
                for (int j = 0; j < 4; j++) {
                    *(u32*)&prow[j * 16]     = pack2bf(st[j][0], st[j][1]);
                    *(u32*)&prow[j * 16 + 2] = pack2bf(st[j][2], st[j][3]);
                }
            }

            bf16x8 vb0[4], vb1[4];
#pragma unroll
            for (int j = 0; j < 4; j++) {
                vb0[j] = *(const bf16x8*)&Vt[(j * 16 + lrow) * LDT_ + quad * 8];
                vb1[j] = *(const bf16x8*)&Vt[(j * 16 + lrow) * LDT_ + 32 + quad * 8];
            }
#pragma unroll
            for (int s = 0; s < 2; s++) {
                if (s == 0 && !do0) continue;
                bf16x8 pa0 = *(const bf16x8*)&Ps[(s * 64 + wave * 16 + lrow) * LDT_ + quad * 8];
                bf16x8 pa1 = *(const bf16x8*)&Ps[(s * 64 + wave * 16 + lrow) * LDT_ + 32 + quad * 8];
#pragma unroll
                for (int jd = 0; jd < 4; jd++) {
                    accO[s][jd] = __builtin_amdgcn_mfma_f32_16x16x32_bf16(pa0, vb0[jd], accO[s][jd], 0, 0, 0);
                    accO[s][jd] = __builtin_amdgcn_mfma_f32_16x16x32_bf16(pa1, vb1[jd], accO[s][jd], 0, 0, 0);
                }
            }
        }

#pragma unroll
        for (int s = 0; s < 2; s++) {
            ls[s] += __shfl_xor(ls[s], 16, 64);
            ls[s] += __shfl_xor(ls[s], 32, 64);
        }
#pragma unroll
        for (int s = 0; s < 2; s++) {
#pragma unroll
            for (int r = 0; r < 4; r++) {
                float lv = __shfl(ls[s], quad * 4 + r, 64);
                float inv = 1.f / lv;
                int t = qt * 128 + s * 64 + wave * 16 + quad * 4 + r;
#pragma unroll
                for (int jd = 0; jd < 4; jd++) {
                    int d = jd * 16 + lrow;
                    O[((size_t)(b_ * T_ + t)) * E_ + h_ * DH_ + d] = f2bf(accO[s][jd][r] * inv);
                }
            }
        }
    };

    run(qaA, qtA);
    run(qaB, qtB);
}

// ---------------- proj GEMM: same pipelined core, C^T float4 stores ----------------
__global__ __launch_bounds__(512, 2) void gemm_proj(
    const ushort* __restrict__ Ob, const ushort* __restrict__ Wb,
    const float* __restrict__ bias, float* __restrict__ out)
{
    __shared__ ushort As[4][256 * 32];
    __shared__ ushort Bs[4][128 * 32];
    const int m0 = blockIdx.x * 256;
    const int n0 = blockIdx.y * 128;
    const int tid  = threadIdx.x;
    const int wave = tid >> 6, lane = tid & 63;
    const int lrow = lane & 15, quad = lane >> 4;
    const int mbase = (wave >> 1) * 64;
    const int nbase = (wave & 1) * 64;
    const int usw = (quad ^ (lrow & 3)) * 8;
    const int sR = lane >> 2;
    const int su = ((lane & 3) ^ (sR & 3)) * 8;

    const ushort* gA0 = Ob + (size_t)(m0 + wave * 16 + sR) * 1024 + su;
    const ushort* gA1 = gA0 + (size_t)128 * 1024;
    const ushort* gB0 = Wb + (size_t)(n0 + wave * 16 + sR) * 1024 + su;

    f32x4 acc[4][4];
#pragma unroll
    for (int i = 0; i < 4; i++)
#pragma unroll
        for (int j = 0; j < 4; j++) acc[i][j] = f32x4{0.f, 0.f, 0.f, 0.f};

    STAGE3(0); STAGE3(1); STAGE3(2);
    asm volatile("s_waitcnt vmcnt(6)" ::: "memory");
    __builtin_amdgcn_s_barrier();
    __builtin_amdgcn_sched_barrier(0);

#pragma unroll 4
    for (int t = 0; t < 29; t++) GPHASE(t, "vmcnt(6)", 1, MFMA_CT);
    GPHASE(29, "vmcnt(3)", 0, MFMA_CT);
    GPHASE(30, "vmcnt(0)", 0, MFMA_CT);
    GPHASE(31, "vmcnt(0)", 0, MFMA_CT);

#pragma unroll
    for (int j = 0; j < 4; j++) {
        int n = n0 + nbase + j * 16 + quad * 4;
        float4 bv = *(const float4*)&bias[n];
#pragma unroll
        for (int i = 0; i < 4; i++) {
            int m = m0 + mbase + i * 16 + lrow;
            float4 o;
            o.x = acc[i][j][0] + bv.x;
            o.y = acc[i][j][1] + bv.y;
            o.z = acc[i][j][2] + bv.z;
            o.w = acc[i][j][3] + bv.w;
            *(float4*)&out[(size_t)m * 1024 + n] = o;
        }
    }
}

extern "C" void kernel_launch(void* const* d_in, const int* in_sizes, int n_in,
                              void* d_out, int out_size, void* d_ws, size_t ws_size,
                              hipStream_t stream) {
    const float* x      = (const float*)d_in[0];
    const float* w_qkv  = (const float*)d_in[1];
    const float* b_qkv  = (const float*)d_in[2];
    const float* w_proj = (const float*)d_in[3];
    const float* b_proj = (const float*)d_in[4];
    float* out = (float*)d_out;

    char* ws = (char*)d_ws;
    ushort* Xb     = (ushort*)ws; ws += (size_t)B_ * T_ * E_ * 2;
    ushort* Wqkvb  = (ushort*)ws; ws += (size_t)3 * E_ * E_ * 2;
    ushort* Wprojb = (ushort*)ws; ws += (size_t)E_ * E_ * 2;
    ushort* Qb     = (ushort*)ws; ws += (size_t)B_ * H_ * T_ * DH_ * 2;
    ushort* Kb     = (ushort*)ws; ws += (size_t)B_ * H_ * T_ * DH_ * 2;
    ushort* Vtb    = (ushort*)ws; ws += (size_t)B_ * H_ * T_ * DH_ * 2;
    ushort* Ob     = (ushort*)ws; ws += (size_t)B_ * T_ * E_ * 2;

    int ntot = (B_ * T_ * E_ + 3 * E_ * E_ + E_ * E_) / 4;
    cvt_all<<<ntot / 256, 256, 0, stream>>>(x, w_qkv, w_proj, Xb, Wqkvb, Wprojb);

    gemm_qkv<<<dim3(32, 24), 512, 0, stream>>>(Xb, Wqkvb, b_qkv, Qb, Kb, Vtb);
    flash_attn<<<dim3(8, 64), 256, 0, stream>>>(Qb, Kb, Vtb, Ob);
    gemm_proj<<<dim3(32, 8), 512, 0, stream>>>(Ob, Wprojb, b_proj, out);
}

// Round 2
// 251.628 us; speedup vs baseline: 1.0300x; 1.0300x over previous
//
#include <hip/hip_runtime.h>
#include <hip/hip_bf16.h>

#define B_ 4
#define T_ 2048
#define E_ 1024
#define H_ 16
#define DH_ 64
#define QSCALE_ 0.18033688f   // 0.125 * log2(e): QK^T comes out in log2 domain

typedef __attribute__((ext_vector_type(8))) short bf16x8;
typedef __attribute__((ext_vector_type(4))) float f32x4;
typedef unsigned int u32;

__device__ inline ushort f2bf(float f) {
    union { float f; unsigned u; } v; v.f = f;
    unsigned r = (v.u + 0x7fffu + ((v.u >> 16) & 1u)) >> 16;
    return (ushort)r;
}

// pack two f32 -> two bf16 (truncation) in one v_perm_b32: a->low, b->high
__device__ inline u32 pack2bf(float a, float b) {
    union { float f; u32 u; } ua, ub; ua.f = a; ub.f = b;
    return __builtin_amdgcn_perm(ub.u, ua.u, 0x07060302);
}

__device__ inline void gload16(const ushort* g, ushort* l) {
    __builtin_amdgcn_global_load_lds((const __attribute__((address_space(1))) u32*)g,
                                     (__attribute__((address_space(3))) u32*)l, 16, 0, 0);
}

// ---------------- fused f32 -> bf16 convert ----------------
__global__ void cvt_all(const float* __restrict__ x, const float* __restrict__ wq,
                        const float* __restrict__ wp,
                        ushort* __restrict__ xo, ushort* __restrict__ wqo, ushort* __restrict__ wpo)
{
    const int NX = B_ * T_ * E_ / 4;
    const int NW = 3 * E_ * E_ / 4;
    int i = blockIdx.x * 256 + threadIdx.x;
    const float* s; ushort* d; int off;
    if (i < NX)            { s = x;  d = xo;  off = i; }
    else if (i < NX + NW)  { s = wq; d = wqo; off = i - NX; }
    else                   { s = wp; d = wpo; off = i - NX - NW; }
    float4 f = ((const float4*)s)[off];
    ushort4 u;
    u.x = f2bf(f.x); u.y = f2bf(f.y); u.z = f2bf(f.z); u.w = f2bf(f.w);
    ((ushort4*)d)[off] = u;
}

// ===========================================================================
// Pipelined GEMM core: 256x128 tile, BK=32, 512 threads (8 waves as 4M x 2N),
// depth-4 LDS ring (96 KiB), counted vmcnt(6), raw s_barrier, setprio MFMA.
// LDS layout (conflict fix, R1): two logical 32-short rows packed per 128B
// LDS row. Logical (row r, 16B-unit u) -> LDS row (r>>1), granule
// ((r&1)*4 + u) ^ ((r>>1)&7).  Staging keeps linear global_load_lds dst
// (1 KiB/wave = 8 LDS rows); per-lane GLOBAL source address is pre-permuted.
// Each 8-lane read group covers all 8 granules bijectively -> 0 conflicts.
// ===========================================================================

// stage tile t_ (A: 256x32 via 2 loads, B: 128x32 via 1 load) into segment t_&3
#define STAGE3(t_) { const int ss_ = (t_) & 3; const int sk_ = (t_) * 32;      \
    gload16(gA0 + sk_, &As[ss_][wave * 512]);                                  \
    gload16(gA1 + sk_, &As[ss_][4096 + wave * 512]);                           \
    gload16(gB0 + sk_, &Bs[ss_][wave * 512]); }

// one phase = one K-tile: ds-read frags | stage t+3 | vmcnt(N) | barrier |
// lgkmcnt(0)+sched_barrier | setprio(1) 16xMFMA setprio(0) | barrier
#define GPHASE(t_, vmstr_, DOSTAGE_, ...) do {                                 \
    const int seg_ = (t_) & 3;                                                 \
    bf16x8 afr[4], bfr[4];                                                     \
    _Pragma("unroll") for (int i_ = 0; i_ < 4; i_++)                           \
        afr[i_] = *(const bf16x8*)&As[seg_][(mbase + i_ * 16) * 32 + rofs];    \
    _Pragma("unroll") for (int j_ = 0; j_ < 4; j_++)                           \
        bfr[j_] = *(const bf16x8*)&Bs[seg_][(nbase + j_ * 16) * 32 + rofs];    \
    if (DOSTAGE_) STAGE3((t_) + 3);                                            \
    asm volatile("s_waitcnt " vmstr_ ::: "memory");                            \
    __builtin_amdgcn_s_barrier();                                              \
    asm volatile("s_waitcnt lgkmcnt(0)" ::: "memory");                         \
    __builtin_amdgcn_sched_barrier(0);                                         \
    __builtin_amdgcn_s_setprio(1);                                             \
    __VA_ARGS__                                                                \
    __builtin_amdgcn_s_setprio(0);                                             \
    __builtin_amdgcn_sched_barrier(0);                                         \
    __builtin_amdgcn_s_barrier();                                              \
    __builtin_amdgcn_sched_barrier(0);                                         \
} while (0)

#define MFMA_QKV                                                               \
    if (ct) {                                                                  \
        _Pragma("unroll") for (int i_ = 0; i_ < 4; i_++)                       \
        _Pragma("unroll") for (int j_ = 0; j_ < 4; j_++)                       \
            acc[i_][j_] = __builtin_amdgcn_mfma_f32_16x16x32_bf16(bfr[j_], afr[i_], acc[i_][j_], 0, 0, 0); \
    } else {                                                                   \
        _Pragma("unroll") for (int i_ = 0; i_ < 4; i_++)                       \
        _Pragma("unroll") for (int j_ = 0; j_ < 4; j_++)                       \
            acc[i_][j_] = __builtin_amdgcn_mfma_f32_16x16x32_bf16(afr[i_], bfr[j_], acc[i_][j_], 0, 0, 0); \
    }

#define MFMA_CT                                                                \
    _Pragma("unroll") for (int i_ = 0; i_ < 4; i_++)                           \
    _Pragma("unroll") for (int j_ = 0; j_ < 4; j_++)                           \
        acc[i_][j_] = __builtin_amdgcn_mfma_f32_16x16x32_bf16(bfr[j_], afr[i_], acc[i_][j_], 0, 0, 0);

// ---------------- QKV GEMM ----------------
__global__ __launch_bounds__(512, 2) void gemm_qkv(
    const ushort* __restrict__ Xb, const ushort* __restrict__ Wb,
    const float* __restrict__ bias,
    ushort* __restrict__ Q, ushort* __restrict__ K, ushort* __restrict__ Vt)
{
    __shared__ ushort As[4][256 * 32];   // 64 KiB
    __shared__ ushort Bs[4][128 * 32];   // 32 KiB
    const int m0 = blockIdx.x * 256;
    const int n0 = blockIdx.y * 128;
    const int kind = n0 >> 10;           // 0=Q 1=K 2=V (block-uniform; 128 | 1024)
    const int tid  = threadIdx.x;
    const int wave = tid >> 6, lane = tid & 63;
    const int lrow = lane & 15, quad = lane >> 4;
    const int mbase = (wave >> 1) * 64;  // 4 M-slices of 64
    const int nbase = (wave & 1) * 64;   // 2 N-slices of 64
    // read offset: LDS row (logical>>1) pairs, granule ((r&1)*4+quad)^(lrow>>1)
    const int rofs = (lrow >> 1) * 64 + (((((lrow & 1) << 2) | quad) ^ (lrow >> 1)) * 8);
    // staging: lane l fills granule l&7 of LDS row (l>>3); invert the swizzle
    const int sx  = (lane & 7) ^ (lane >> 3);
    const int sRl = 2 * (lane >> 3) + (sx >> 2);   // logical row within 16-row group
    const int su  = (sx & 3) * 8;                  // unit offset in shorts

    const ushort* gA0 = Xb + (size_t)(m0 + wave * 16 + sRl) * 1024 + su;
    const ushort* gA1 = gA0 + (size_t)128 * 1024;
    const ushort* gB0 = Wb + (size_t)(n0 + wave * 16 + sRl) * 1024 + su;

    const int b = m0 >> 11;              // batch (256 | 2048)
    const bool ct = (kind != 2);

    f32x4 acc[4][4];
#pragma unroll
    for (int i = 0; i < 4; i++)
#pragma unroll
        for (int j = 0; j < 4; j++) acc[i][j] = f32x4{0.f, 0.f, 0.f, 0.f};

    // prologue: stage tiles 0,1,2; wait tile 0 (6 loads of tiles 1,2 in flight)
    STAGE3(0); STAGE3(1); STAGE3(2);
    asm volatile("s_waitcnt vmcnt(6)" ::: "memory");
    __builtin_amdgcn_s_barrier();
    __builtin_amdgcn_sched_barrier(0);

#pragma unroll 4
    for (int t = 0; t < 29; t++) GPHASE(t, "vmcnt(6)", 1, MFMA_QKV);
    GPHASE(29, "vmcnt(3)", 0, MFMA_QKV);
    GPHASE(30, "vmcnt(0)", 0, MFMA_QKV);
    GPHASE(31, "vmcnt(0)", 0, MFMA_QKV);

    if (ct) {
        // C^T: lane holds m = mbase+i*16+lrow, n = nbase+j*16+quad*4+r -> ushort4 along d
        ushort* dst = (kind == 0) ? Q : K;
        const float scale = (kind == 0) ? QSCALE_ : 1.f;
#pragma unroll
        for (int j = 0; j < 4; j++) {
            int nq = (n0 & 1023) + nbase + j * 16 + quad * 4;
            int h = nq >> 6, d = nq & 63;
            float4 bv = *(const float4*)&bias[n0 + nbase + j * 16 + quad * 4];
            size_t bh = (size_t)(b * H_ + h);
#pragma unroll
            for (int i = 0; i < 4; i++) {
                int t = (m0 + mbase + i * 16 + lrow) & 2047;   // batch-local!
                ushort4 o;
                o.x = f2bf((acc[i][j][0] + bv.x) * scale);
                o.y = f2bf((acc[i][j][1] + bv.y) * scale);
                o.z = f2bf((acc[i][j][2] + bv.z) * scale);
                o.w = f2bf((acc[i][j][3] + bv.w) * scale);
                *(ushort4*)&dst[(bh * T_ + t) * DH_ + d] = o;
            }
        }
    } else {
        // normal: lane holds n = nbase+j*16+lrow, t = mbase+i*16+quad*4+r -> ushort4 along t
#pragma unroll
        for (int j = 0; j < 4; j++) {
            int nv = (n0 & 1023) + nbase + j * 16 + lrow;
            int h = nv >> 6, d = nv & 63;
            float bv = bias[n0 + nbase + j * 16 + lrow];
            size_t bh = (size_t)(b * H_ + h);
#pragma unroll
            for (int i = 0; i < 4; i++) {
                int t = (m0 + mbase + i * 16 + quad * 4) & 2047;   // batch-local!
                ushort4 o;
                o.x = f2bf(acc[i][j][0] + bv);
                o.y = f2bf(acc[i][j][1] + bv);
                o.z = f2bf(acc[i][j][2] + bv);
                o.w = f2bf(acc[i][j][3] + bv);
                *(ushort4*)&Vt[(bh * DH_ + d) * T_ + t] = o;
            }
        }
    }
}

// ---------------- Flash attention: paired q-tiles (R8-proven version) ----------------
#define LDT_ 76

__global__ __launch_bounds__(256) void flash_attn(
    const ushort* __restrict__ Q, const ushort* __restrict__ K,
    const ushort* __restrict__ Vg,   // [bh][DH][T]
    ushort* __restrict__ O)
{
    __shared__ ushort Ks[64 * LDT_];
    __shared__ ushort Vt[64 * LDT_];
    __shared__ ushort Ps[128 * LDT_];   // doubles as Q staging

    const int qtA = 15 - blockIdx.x;     // long tile
    const int qtB = blockIdx.x;          // short tile
    const int bh = blockIdx.y;
    const int tid  = threadIdx.x;
    const int wave = tid >> 6, lane = tid & 63;
    const int lrow = lane & 15, quad = lane >> 4;
    const int sr = tid >> 2, sc = (tid & 3) * 16;   // K/V staging coords

    const ushort* Qbh = Q  + (size_t)bh * T_ * DH_;
    const ushort* Kbh = K  + (size_t)bh * T_ * DH_;
    const ushort* Vbh = Vg + (size_t)bh * DH_ * T_;
    const int b_ = bh >> 4, h_ = bh & 15;

    auto stageQ = [&](int qt, bf16x8 qa[2][2]) {
        int qr = tid >> 1, qc = (tid & 1) * 32;
        const ushort* src = &Qbh[(size_t)(qt * 128 + qr) * DH_ + qc];
#pragma unroll
        for (int i = 0; i < 4; i++)
            *(int4*)&Ps[qr * LDT_ + qc + 8 * i] = *(const int4*)&src[8 * i];
        __syncthreads();
#pragma unroll
        for (int s = 0; s < 2; s++)
#pragma unroll
            for (int h = 0; h < 2; h++)
                qa[s][h] = *(const bf16x8*)&Ps[(s * 64 + wave * 16 + lrow) * LDT_ + h * 32 + quad * 8];
    };

    bf16x8 qaA[2][2], qaB[2][2];
    stageQ(qtA, qaA);
    __syncthreads();
    stageQ(qtB, qaB);

    auto run = [&](const bf16x8 (&qa)[2][2], int qt) {
        const int lastkt = 2 * qt + 1;

        int4 kr0 = *(const int4*)&Kbh[(size_t)sr * DH_ + sc];
        int4 kr1 = *(const int4*)&Kbh[(size_t)sr * DH_ + sc + 8];
        int4 vr0 = *(const int4*)&Vbh[(size_t)sr * T_ + sc];
        int4 vr1 = *(const int4*)&Vbh[(size_t)sr * T_ + sc + 8];

        float ls[2] = {0.f, 0.f};
        f32x4 accO[2][4];
#pragma unroll
        for (int s = 0; s < 2; s++)
#pragma unroll
            for (int j = 0; j < 4; j++) accO[s][j] = f32x4{0.f, 0.f, 0.f, 0.f};

        for (int kt = 0; kt <= lastkt; ++kt) {
            __syncthreads();
            *(int4*)&Ks[sr * LDT_ + sc]     = kr0;
            *(int4*)&Ks[sr * LDT_ + sc + 8] = kr1;
            *(int4*)&Vt[sr * LDT_ + sc]     = vr0;
            *(int4*)&Vt[sr * LDT_ + sc + 8] = vr1;
            __syncthreads();
            if (kt < lastkt) {
                kr0 = *(const int4*)&Kbh[(size_t)((kt + 1) * 64 + sr) * DH_ + sc];
                kr1 = *(const int4*)&Kbh[(size_t)((kt + 1) * 64 + sr) * DH_ + sc + 8];
                vr0 = *(const int4*)&Vbh[(size_t)sr * T_ + (kt + 1) * 64 + sc];
                vr1 = *(const int4*)&Vbh[(size_t)sr * T_ + (kt + 1) * 64 + sc + 8];
            }

            bf16x8 kb0[4], kb1[4];
#pragma unroll
            for (int j = 0; j < 4; j++) {
                kb0[j] = *(const bf16x8*)&Ks[(j * 16 + lrow) * LDT_ + quad * 8];
                kb1[j] = *(const bf16x8*)&Ks[(j * 16 + lrow) * LDT_ + 32 + quad * 8];
            }

            const bool do0 = (kt != lastkt);
#pragma unroll
            for (int s = 0; s < 2; s++) {
                if (s == 0 && !do0) continue;
                f32x4 st[4];
#pragma unroll
                for (int j = 0; j < 4; j++) {
                    f32x4 sj = f32x4{0.f, 0.f, 0.f, 0.f};
                    sj = __builtin_amdgcn_mfma_f32_16x16x32_bf16(kb0[j], qa[s][0], sj, 0, 0, 0);
                    sj = __builtin_amdgcn_mfma_f32_16x16x32_bf16(kb1[j], qa[s][1], sj, 0, 0, 0);
                    st[j] = sj;
                }
                if (kt == 2 * qt + s) {
                    const int qrow = qt * 128 + s * 64 + wave * 16 + lrow;
                    const int keyb = kt * 64 + quad * 4;
#pragma unroll
                    for (int j = 0; j < 4; j++)
#pragma unroll
                        for (int r = 0; r < 4; r++)
                            if (keyb + j * 16 + r > qrow) st[j][r] = -1e30f;
                }
                float lp = 0.f;
#pragma unroll
                for (int j = 0; j < 4; j++)
#pragma unroll
                    for (int r = 0; r < 4; r++) {
                        float p = __builtin_amdgcn_exp2f(st[j][r]);
                        st[j][r] = p;
                        lp += p;
                    }
                ls[s] += lp;
                ushort* prow = &Ps[(s * 64 + wave * 16 + lrow) * LDT_ + quad * 4];
#pragma unroll
                for (int j = 0; j < 4; j++) {
                    *(u32*)&prow[j * 16]     = pack2bf(st[j][0], st[j][1]);
                    *(u32*)&prow[j * 16 + 2] = pack2bf(st[j][2], st[j][3]);
                }
            }

            bf16x8 vb0[4], vb1[4];
#pragma unroll
            for (int j = 0; j < 4; j++) {
                vb0[j] = *(const bf16x8*)&Vt[(j * 16 + lrow) * LDT_ + quad * 8];
                vb1[j] = *(const bf16x8*)&Vt[(j * 16 + lrow) * LDT_ + 32 + quad * 8];
            }
#pragma unroll
            for (int s = 0; s < 2; s++) {
                if (s == 0 && !do0) continue;
                bf16x8 pa0 = *(const bf16x8*)&Ps[(s * 64 + wave * 16 + lrow) * LDT_ + quad * 8];
                bf16x8 pa1 = *(const bf16x8*)&Ps[(s * 64 + wave * 16 + lrow) * LDT_ + 32 + quad * 8];
#pragma unroll
                for (int jd = 0; jd < 4; jd++) {
                    accO[s][jd] = __builtin_amdgcn_mfma_f32_16x16x32_bf16(pa0, vb0[jd], accO[s][jd], 0, 0, 0);
                    accO[s][jd] = __builtin_amdgcn_mfma_f32_16x16x32_bf16(pa1, vb1[jd], accO[s][jd], 0, 0, 0);
                }
            }
        }

#pragma unroll
        for (int s = 0; s < 2; s++) {
            ls[s] += __shfl_xor(ls[s], 16, 64);
            ls[s] += __shfl_xor(ls[s], 32, 64);
        }
#pragma unroll
        for (int s = 0; s < 2; s++) {
#pragma unroll
            for (int r = 0; r < 4; r++) {
                float lv = __shfl(ls[s], quad * 4 + r, 64);
                float inv = 1.f / lv;
                int t = qt * 128 + s * 64 + wave * 16 + quad * 4 + r;
#pragma unroll
                for (int jd = 0; jd < 4; jd++) {
                    int d = jd * 16 + lrow;
                    O[((size_t)(b_ * T_ + t)) * E_ + h_ * DH_ + d] = f2bf(accO[s][jd][r] * inv);
                }
            }
        }
    };

    run(qaA, qtA);
    run(qaB, qtB);
}

// ---------------- proj GEMM: same pipelined core, C^T float4 stores ----------------
__global__ __launch_bounds__(512, 2) void gemm_proj(
    const ushort* __restrict__ Ob, const ushort* __restrict__ Wb,
    const float* __restrict__ bias, float* __restrict__ out)
{
    __shared__ ushort As[4][256 * 32];
    __shared__ ushort Bs[4][128 * 32];
    const int m0 = blockIdx.x * 256;
    const int n0 = blockIdx.y * 128;
    const int tid  = threadIdx.x;
    const int wave = tid >> 6, lane = tid & 63;
    const int lrow = lane & 15, quad = lane >> 4;
    const int mbase = (wave >> 1) * 64;
    const int nbase = (wave & 1) * 64;
    const int rofs = (lrow >> 1) * 64 + (((((lrow & 1) << 2) | quad) ^ (lrow >> 1)) * 8);
    const int sx  = (lane & 7) ^ (lane >> 3);
    const int sRl = 2 * (lane >> 3) + (sx >> 2);
    const int su  = (sx & 3) * 8;

    const ushort* gA0 = Ob + (size_t)(m0 + wave * 16 + sRl) * 1024 + su;
    const ushort* gA1 = gA0 + (size_t)128 * 1024;
    const ushort* gB0 = Wb + (size_t)(n0 + wave * 16 + sRl) * 1024 + su;

    f32x4 acc[4][4];
#pragma unroll
    for (int i = 0; i < 4; i++)
#pragma unroll
        for (int j = 0; j < 4; j++) acc[i][j] = f32x4{0.f, 0.f, 0.f, 0.f};

    STAGE3(0); STAGE3(1); STAGE3(2);
    asm volatile("s_waitcnt vmcnt(6)" ::: "memory");
    __builtin_amdgcn_s_barrier();
    __builtin_amdgcn_sched_barrier(0);

#pragma unroll 4
    for (int t = 0; t < 29; t++) GPHASE(t, "vmcnt(6)", 1, MFMA_CT);
    GPHASE(29, "vmcnt(3)", 0, MFMA_CT);
    GPHASE(30, "vmcnt(0)", 0, MFMA_CT);
    GPHASE(31, "vmcnt(0)", 0, MFMA_CT);

#pragma unroll
    for (int j = 0; j < 4; j++) {
        int n = n0 + nbase + j * 16 + quad * 4;
        float4 bv = *(const float4*)&bias[n];
#pragma unroll
        for (int i = 0; i < 4; i++) {
            int m = m0 + mbase + i * 16 + lrow;
            float4 o;
            o.x = acc[i][j][0] + bv.x;
            o.y = acc[i][j][1] + bv.y;
            o.z = acc[i][j][2] + bv.z;
            o.w = acc[i][j][3] + bv.w;
            *(float4*)&out[(size_t)m * 1024 + n] = o;
        }
    }
}

extern "C" void kernel_launch(void* const* d_in, const int* in_sizes, int n_in,
                              void* d_out, int out_size, void* d_ws, size_t ws_size,
                              hipStream_t stream) {
    const float* x      = (const float*)d_in[0];
    const float* w_qkv  = (const float*)d_in[1];
    const float* b_qkv  = (const float*)d_in[2];
    const float* w_proj = (const float*)d_in[3];
    const float* b_proj = (const float*)d_in[4];
    float* out = (float*)d_out;

    char* ws = (char*)d_ws;
    ushort* Xb     = (ushort*)ws; ws += (size_t)B_ * T_ * E_ * 2;
    ushort* Wqkvb  = (ushort*)ws; ws += (size_t)3 * E_ * E_ * 2;
    ushort* Wprojb = (ushort*)ws; ws += (size_t)E_ * E_ * 2;
    ushort* Qb     = (ushort*)ws; ws += (size_t)B_ * H_ * T_ * DH_ * 2;
    ushort* Kb     = (ushort*)ws; ws += (size_t)B_ * H_ * T_ * DH_ * 2;
    ushort* Vtb    = (ushort*)ws; ws += (size_t)B_ * H_ * T_ * DH_ * 2;
    ushort* Ob     = (ushort*)ws; ws += (size_t)B_ * T_ * E_ * 2;

    int ntot = (B_ * T_ * E_ + 3 * E_ * E_ + E_ * E_) / 4;
    cvt_all<<<ntot / 256, 256, 0, stream>>>(x, w_qkv, w_proj, Xb, Wqkvb, Wprojb);

    gemm_qkv<<<dim3(32, 24), 512, 0, stream>>>(Xb, Wqkvb, b_qkv, Qb, Kb, Vtb);
    flash_attn<<<dim3(8, 64), 256, 0, stream>>>(Qb, Kb, Vtb, Ob);
    gemm_proj<<<dim3(32, 8), 512, 0, stream>>>(Ob, Wprojb, b_proj, out);
}